// Round 16
// baseline (388.538 us; speedup 1.0000x reference)
//
#include <hip/hip_runtime.h>
#include <math.h>

#define Cc     8
#define FIELD  7
#define PAD    3
#define TW     32        // tile width
#define TH     16        // tile height
#define QSTR   39        // qs row stride (uint4); col 38 = pad col (staged, zero weight)
#define NSTG   (22*QSTR) // 858 staged uint4 per tile
#define BB     32
#define HH     384
#define WW     384
#define NB     4         // batches per block (software-pipelined)
#define NSLOT  64        // 8 dy' x 8 dx slots (dx==7 zero-pad) for a row-PAIR
#define IP     4         // pixels per thread in init_qv
#define UCLIP  13.815510557964274f   // -log(1e-6)

typedef __attribute__((ext_vector_type(8))) short short8;  // 8 bf16 = 4 VGPRs
typedef __attribute__((ext_vector_type(4))) float f32x4;   // MFMA C/D
typedef __attribute__((ext_vector_type(4))) float fvec4;   // native vec for nt builtins
typedef __attribute__((ext_vector_type(4))) unsigned uvec4;

__device__ __forceinline__ unsigned short f2bf(float f) {   // RNE fp32->bf16
    unsigned u = __float_as_uint(f);
    u += 0x7FFFu + ((u >> 16) & 1u);
    return (unsigned short)(u >> 16);
}
__device__ __forceinline__ unsigned short f2h(float f) {    // RNE fp32->fp16
    return __builtin_bit_cast(unsigned short, (_Float16)f);
}
__device__ __forceinline__ float hlo(unsigned u) {
    return (float)__builtin_bit_cast(_Float16, (unsigned short)(u & 0xFFFFu));
}
__device__ __forceinline__ float hhi(unsigned u) {
    return (float)__builtin_bit_cast(_Float16, (unsigned short)(u >> 16));
}
// STORE-side only nontemporal for q (write-once): R15 showed nt LOADS regress
// (halo reads have 1.68x inter-block L2 reuse); the write-side dirty-evict
// theory (mid WRITE_SIZE 170 MB vs 75.5 MB q_out) is tested here in isolation.
__device__ __forceinline__ void ntstore_u4(uint4* p, uint4 v) {
    __builtin_nontemporal_store(__builtin_bit_cast(uvec4, v), (uvec4*)p);
}

// ---------------------------------------------------------------------------
// init_qv (+ folded prep_w): q0 = softmax(x) bf16x8; v = b - u@W
// (u = min(lse-x, UCLIP)); v fp16 (vh) when half!=0, else fp32 (vf).
// IP=4 pixels/thread, 8 float4 loads in flight (R14-verified). q0 stored
// nontemporal (write-once); vh stored cached (read 5x).
// Blocks 0-1 also compute the 64-slot weight table (folded prep_w).
// ---------------------------------------------------------------------------
__global__ __launch_bounds__(256)
void init_qv(const float* __restrict__ x, const float* __restrict__ sw,
             const float* __restrict__ sb,
             uint4* __restrict__ q0, float* __restrict__ vf,
             uint4* __restrict__ vh, int half,
             const float* __restrict__ kw, unsigned short* __restrict__ wtab) {
    if (blockIdx.x < 2) {
        int it = blockIdx.x * 256 + threadIdx.x;
        if (it < NSLOT * 8) {
            int s = it >> 3, j = it & 7;
            int dyp = s >> 3, dx = s & 7;
#pragma unroll
            for (int n = 0; n < 16; ++n) {
                int h = n >> 3, d = n & 7;
                int dy = dyp - h;
                float a = 0.f;
                if (dy >= 0 && dy < FIELD && dx < 7) {
                    int tap = dy * 7 + dx;
#pragma unroll
                    for (int c = 0; c < Cc; ++c) {
                        float kv = (c == j) ? 0.f : kw[(tap * Cc + j) * Cc + c];
                        a = fmaf(kv, sw[c * Cc + d], a);
                    }
                }
                wtab[(s * 16 + n) * 8 + j] = f2bf(a);
            }
        }
    }

    const long long STRD = (long long)BB * HH * WW / IP;
    const long long pb = (long long)blockIdx.x * 256 + threadIdx.x;

    fvec4 xr[IP][2];
#pragma unroll
    for (int k = 0; k < IP; ++k) {
        const fvec4* xp = (const fvec4*)(x + (pb + k * STRD) * Cc);
        xr[k][0] = __builtin_nontemporal_load(xp);
        xr[k][1] = __builtin_nontemporal_load(xp + 1);
    }

#pragma unroll
    for (int k = 0; k < IP; ++k) {
        const long long p = pb + k * STRD;
        float xv[Cc] = {xr[k][0].x, xr[k][0].y, xr[k][0].z, xr[k][0].w,
                        xr[k][1].x, xr[k][1].y, xr[k][1].z, xr[k][1].w};
        float m = xv[0];
#pragma unroll
        for (int c = 1; c < Cc; ++c) m = fmaxf(m, xv[c]);
        float s = 0.f, e[Cc];
#pragma unroll
        for (int c = 0; c < Cc; ++c) { e[c] = __expf(xv[c] - m); s += e[c]; }
        float inv = 1.f / s;
        uint4 qo;
        qo.x = f2bf(e[0] * inv) | ((unsigned)f2bf(e[1] * inv) << 16);
        qo.y = f2bf(e[2] * inv) | ((unsigned)f2bf(e[3] * inv) << 16);
        qo.z = f2bf(e[4] * inv) | ((unsigned)f2bf(e[5] * inv) << 16);
        qo.w = f2bf(e[6] * inv) | ((unsigned)f2bf(e[7] * inv) << 16);
        ntstore_u4(&q0[p], qo);

        float lse = m + __logf(s);
        float u[Cc];
#pragma unroll
        for (int c = 0; c < Cc; ++c) u[c] = fminf(lse - xv[c], UCLIP);
        float vv[Cc];
#pragma unroll
        for (int d = 0; d < Cc; ++d) {
            float a = sb[d];
#pragma unroll
            for (int c = 0; c < Cc; ++c) a = fmaf(-u[c], sw[c * Cc + d], a);
            vv[d] = a;
        }
        if (half) {
            uint4 vo;
            vo.x = f2h(vv[0]) | ((unsigned)f2h(vv[1]) << 16);
            vo.y = f2h(vv[2]) | ((unsigned)f2h(vv[3]) << 16);
            vo.z = f2h(vv[4]) | ((unsigned)f2h(vv[5]) << 16);
            vo.w = f2h(vv[6]) | ((unsigned)f2h(vv[7]) << 16);
            vh[p] = vo;
        } else {
            float4* vp = (float4*)(vf + p * Cc);
            vp[0] = make_float4(vv[0], vv[1], vv[2], vv[3]);
            vp[1] = make_float4(vv[4], vv[5], vv[6], vv[7]);
        }
    }
}

// ---------------------------------------------------------------------------
// mrf_iter: R7/R8/R11/R14-verified iteration kernel (VHALF: v fp16/fp32).
// NB=4 batch pipeline, double-buffered qs, operand-swapped row-pair MFMA
// (dx-major K, read-dedup, 0 conflicts), in-register softmax, 1 barrier/tile.
// R16: q_out stores nontemporal (write-once; dirty-evict theory); staging
// loads CACHED (R15 lesson: halo reads have inter-block L2 reuse); last-iter
// logits nontemporal (R14-verified).
// ---------------------------------------------------------------------------
template<int VHALF>
__global__ __launch_bounds__(512)
void mrf_iter(const uint4* __restrict__ qin,
              const unsigned short* __restrict__ wtab,
              const void* __restrict__ vsrc,
              uint4* __restrict__ qout,
              float* __restrict__ lout,
              int last) {
    __shared__ __align__(16) uint4 qs[2][NSTG];

    const int tid = threadIdx.x;
    const int wv  = tid >> 6;
    const int l   = tid & 63;
    const int m   = l & 15;
    const int g   = l >> 4;

    const int w0 = blockIdx.x * TW;
    const int h0 = blockIdx.y * TH;
    const int b0 = blockIdx.z * NB;

    const int r0 = 4 * (wv >> 1);
    const int cx = 16 * (wv & 1);

    const int p   = g & 1;
    const int row = r0 + 2 * p + (g >> 1);
    const int px  = cx + m;
    const long long pixoff = (long long)(h0 + row) * WW + (w0 + px);
    const long long BSTR   = (long long)HH * WW;

    short8 bw[8][2];
#pragma unroll
    for (int dyq = 0; dyq < 8; ++dyq)
#pragma unroll
        for (int dxb = 0; dxb < 2; ++dxb) {
            int s = dyq * 8 + 4 * dxb + g;
            uint4 t = *(const uint4*)(wtab + (s * 16 + m) * 8);
            bw[dyq][dxb] = __builtin_bit_cast(short8, t);
        }

    const int sy0 = tid / QSTR, sx0 = tid - sy0 * QSTR;
    const int gh0 = h0 + sy0 - PAD, gw0 = w0 + sx0 - PAD;
    const bool in0 = (gh0 >= 0 && gh0 < HH && gw0 >= 0 && gw0 < WW);
    const long long off0 = (long long)gh0 * WW + gw0;
    const int  s1  = tid + 512;
    const bool has1 = (s1 < NSTG);
    const int sy1 = s1 / QSTR, sx1 = s1 - sy1 * QSTR;
    const int gh1 = h0 + sy1 - PAD, gw1 = w0 + sx1 - PAD;
    const bool in1 = has1 && (gh1 >= 0 && gh1 < HH && gw1 >= 0 && gw1 < WW);
    const long long off1 = (long long)gh1 * WW + gw1;

    const uint4* qb = qin + b0 * BSTR;
    const uint4  zz = make_uint4(0, 0, 0, 0);

    uint4 c0 = in0 ? qb[off0] : zz;
    uint4 c1 = in1 ? qb[off1] : zz;
    uint4  vhv = zz;
    float4 v0, v1;
    if constexpr (VHALF) {
        vhv = ((const uint4*)vsrc)[b0 * BSTR + pixoff];
    } else {
        const float4* vp0 = (const float4*)((const float*)vsrc + (b0 * BSTR + pixoff) * Cc);
        v0 = vp0[0]; v1 = vp0[1];
    }
    qs[0][tid] = c0;
    if (has1) qs[0][s1] = c1;
    __syncthreads();

#pragma unroll
    for (int t = 0; t < NB; ++t) {
        uint4 n0 = zz, n1 = zz, vhn = zz;
        float4 vn0 = make_float4(0.f, 0.f, 0.f, 0.f), vn1 = vn0;
        if (t + 1 < NB) {
            const uint4* qbn = qb + (t + 1) * BSTR;
            n0 = in0 ? qbn[off0] : zz;
            n1 = in1 ? qbn[off1] : zz;
            if constexpr (VHALF) {
                vhn = ((const uint4*)vsrc)[(b0 + t + 1) * BSTR + pixoff];
            } else {
                const float4* vpn = (const float4*)((const float*)vsrc + ((b0 + t + 1) * BSTR + pixoff) * Cc);
                vn0 = vpn[0]; vn1 = vpn[1];
            }
        }

        f32x4 acc0 = (f32x4){0.f, 0.f, 0.f, 0.f};
        f32x4 acc1 = (f32x4){0.f, 0.f, 0.f, 0.f};
        const uint4* Q = qs[t & 1];
        const int colbase = cx + m + g;
#pragma unroll
        for (int dyp = 0; dyp < 10; ++dyp) {
            const int rb = (r0 + dyp) * QSTR + colbase;
#pragma unroll
            for (int dxb = 0; dxb < 2; ++dxb) {
                short8 qv = *(const short8*)&Q[rb + 4 * dxb];
                if (dyp < 8)
                    acc0 = __builtin_amdgcn_mfma_f32_16x16x32_bf16(bw[dyp][dxb], qv, acc0, 0, 0, 0);
                if (dyp >= 2)
                    acc1 = __builtin_amdgcn_mfma_f32_16x16x32_bf16(bw[dyp - 2][dxb], qv, acc1, 0, 0, 0);
            }
        }

        float o[Cc];
#pragma unroll
        for (int tt = 0; tt < 4; ++tt) {
            float s0v = __shfl_xor(acc0[tt], 16);
            float s1v = __shfl_xor(acc1[tt], 16);
            o[tt]     = p ? s1v      : acc0[tt];
            o[4 + tt] = p ? acc1[tt] : s0v;
        }

        float vv[Cc];
        if constexpr (VHALF) {
            vv[0] = hlo(vhv.x); vv[1] = hhi(vhv.x);
            vv[2] = hlo(vhv.y); vv[3] = hhi(vhv.y);
            vv[4] = hlo(vhv.z); vv[5] = hhi(vhv.z);
            vv[6] = hlo(vhv.w); vv[7] = hhi(vhv.w);
        } else {
            vv[0] = v0.x; vv[1] = v0.y; vv[2] = v0.z; vv[3] = v0.w;
            vv[4] = v1.x; vv[5] = v1.y; vv[6] = v1.z; vv[7] = v1.w;
        }
#pragma unroll
        for (int d = 0; d < Cc; ++d) o[d] = vv[d] - o[d];
        const long long pix = (b0 + t) * BSTR + pixoff;
        if (last) {
            fvec4* op = (fvec4*)(lout + pix * Cc);
            fvec4 w0v = {o[0], o[1], o[2], o[3]};
            fvec4 w1v = {o[4], o[5], o[6], o[7]};
            __builtin_nontemporal_store(w0v, op);
            __builtin_nontemporal_store(w1v, op + 1);
        } else {
            float mm = o[0];
#pragma unroll
            for (int d = 1; d < Cc; ++d) mm = fmaxf(mm, o[d]);
            float ss = 0.f, e[Cc];
#pragma unroll
            for (int d = 0; d < Cc; ++d) { e[d] = __expf(o[d] - mm); ss += e[d]; }
            float inv = 1.f / ss;
            uint4 qo;
            qo.x = f2bf(e[0] * inv) | ((unsigned)f2bf(e[1] * inv) << 16);
            qo.y = f2bf(e[2] * inv) | ((unsigned)f2bf(e[3] * inv) << 16);
            qo.z = f2bf(e[4] * inv) | ((unsigned)f2bf(e[5] * inv) << 16);
            qo.w = f2bf(e[6] * inv) | ((unsigned)f2bf(e[7] * inv) << 16);
            ntstore_u4(&qout[pix], qo);
        }

        if (t + 1 < NB) {
            qs[(t + 1) & 1][tid] = n0;
            if (has1) qs[(t + 1) & 1][s1] = n1;
            __syncthreads();
            if constexpr (VHALF) { vhv = vhn; } else { v0 = vn0; v1 = vn1; }
        }
    }
}

extern "C" void kernel_launch(void* const* d_in, const int* in_sizes, int n_in,
                              void* d_out, int out_size, void* d_ws, size_t ws_size,
                              hipStream_t stream) {
    (void)in_sizes; (void)n_in; (void)out_size;
    const float* x  = (const float*)d_in[0];   // [32,384,384,8]
    const float* kw = (const float*)d_in[1];   // [7,7,8,8]
    const float* sw = (const float*)d_in[2];   // [8,8]
    const float* sb = (const float*)d_in[3];   // [8]

    const size_t QSZ = (size_t)BB * HH * WW * 16;   // 75,497,472 B (bf16x8)
    const size_t VSZ = (size_t)BB * HH * WW * 16;   // 75,497,472 B (fp16x8)
    uint4* qA = (uint4*)d_ws;
    uint4* qB = (uint4*)((char*)d_ws + QSZ);

    const long long npix = (long long)BB * HH * WW;
    dim3 grid(WW / TW, HH / TH, BB / NB);   // 12 x 24 x 8
    const int initBlocks = (int)(npix / (256 * IP));   // 4608

    if (ws_size >= 2 * QSZ + VSZ + 16384) {
        // fp16-v path: v (75.5 MB, read 5x) is the cached stream; q writes bypass
        uint4* vh = (uint4*)((char*)d_ws + 2 * QSZ);
        unsigned short* wt = (unsigned short*)((char*)d_ws + 2 * QSZ + VSZ);
        init_qv<<<initBlocks, 256, 0, stream>>>(x, sw, sb, qA, nullptr, vh, 1, kw, wt);
        mrf_iter<1><<<grid, 512, 0, stream>>>(qA, wt, vh, qB, nullptr, 0);
        mrf_iter<1><<<grid, 512, 0, stream>>>(qB, wt, vh, qA, nullptr, 0);
        mrf_iter<1><<<grid, 512, 0, stream>>>(qA, wt, vh, qB, nullptr, 0);
        mrf_iter<1><<<grid, 512, 0, stream>>>(qB, wt, vh, qA, nullptr, 0);
        mrf_iter<1><<<grid, 512, 0, stream>>>(qA, wt, vh, nullptr, (float*)d_out, 1);
    } else {
        // fallback: fp32-v-in-d_out path (R7-verified structure)
        float* vbuf = (float*)d_out;
        unsigned short* wt = (unsigned short*)((char*)d_ws + 2 * QSZ);
        init_qv<<<initBlocks, 256, 0, stream>>>(x, sw, sb, qA, vbuf, nullptr, 0, kw, wt);
        mrf_iter<0><<<grid, 512, 0, stream>>>(qA, wt, vbuf, qB, nullptr, 0);
        mrf_iter<0><<<grid, 512, 0, stream>>>(qB, wt, vbuf, qA, nullptr, 0);
        mrf_iter<0><<<grid, 512, 0, stream>>>(qA, wt, vbuf, qB, nullptr, 0);
        mrf_iter<0><<<grid, 512, 0, stream>>>(qB, wt, vbuf, qA, nullptr, 0);
        mrf_iter<0><<<grid, 512, 0, stream>>>(qA, wt, vbuf, nullptr, (float*)d_out, 1);
    }
}

// Round 18
// 345.629 us; speedup vs baseline: 1.1241x; 1.1241x over previous
//
#include <hip/hip_runtime.h>
#include <math.h>

#define Cc     8
#define FIELD  7
#define PAD    3
#define TW     32        // tile width
#define TH     16        // tile height
#define QSTR   39        // qs row stride (uint4); col 38 = pad col (staged, zero weight)
#define NSTG   (22*QSTR) // 858 staged uint4 per tile
#define BB     32
#define HH     384
#define WW     384
#define NB     4         // batches per block (software-pipelined)
#define NSLOT  64        // 8 dy' x 8 dx slots (dx==7 zero-pad) for a row-PAIR
#define IP     4         // pixels per thread in init_qv
#define UCLIP  13.815510557964274f   // -log(1e-6)

typedef __attribute__((ext_vector_type(8))) short short8;  // 8 bf16 = 4 VGPRs
typedef __attribute__((ext_vector_type(4))) float f32x4;   // MFMA C/D
typedef __attribute__((ext_vector_type(4))) float fvec4;   // native vec for nontemporal builtins

// R14-exact configuration: cached q stores + cached staging loads (R15/R16
// showed nt hints on the q path regress: nt loads kill halo L2 reuse, nt
// stores kill the write->next-read L2/L3 service and store throughput).
__device__ __forceinline__ unsigned short f2bf(float f) {   // RNE fp32->bf16
    unsigned u = __float_as_uint(f);
    u += 0x7FFFu + ((u >> 16) & 1u);
    return (unsigned short)(u >> 16);
}
__device__ __forceinline__ unsigned short f2h(float f) {    // RNE fp32->fp16
    return __builtin_bit_cast(unsigned short, (_Float16)f);
}
__device__ __forceinline__ float hlo(unsigned u) {
    return (float)__builtin_bit_cast(_Float16, (unsigned short)(u & 0xFFFFu));
}
__device__ __forceinline__ float hhi(unsigned u) {
    return (float)__builtin_bit_cast(_Float16, (unsigned short)(u >> 16));
}

// ---------------------------------------------------------------------------
// init_qv (+ folded prep_w): q0 = softmax(x) bf16x8; v = b - u@W
// (u = min(lse-x, UCLIP)); v fp16 (vh) when half!=0, else fp32 (vf).
// IP=4 pixels/thread at stride npix/4 -> 8 coalesced float4 loads in flight
// per thread (MLP for the latency-bound softmax/v chain).
// Blocks 0-1 additionally compute the 64-slot fused weight table (dx-major,
// R6/R7-verified layout) -- removes the separate prep_w launch.
// ---------------------------------------------------------------------------
__global__ __launch_bounds__(256)
void init_qv(const float* __restrict__ x, const float* __restrict__ sw,
             const float* __restrict__ sb,
             uint4* __restrict__ q0, float* __restrict__ vf,
             uint4* __restrict__ vh, int half,
             const float* __restrict__ kw, unsigned short* __restrict__ wtab) {
    // --- folded prep_w (512 threads cover 512 (slot,j) items; 408 real) ---
    if (blockIdx.x < 2) {
        int it = blockIdx.x * 256 + threadIdx.x;
        if (it < NSLOT * 8) {
            int s = it >> 3, j = it & 7;
            int dyp = s >> 3, dx = s & 7;
#pragma unroll
            for (int n = 0; n < 16; ++n) {
                int h = n >> 3, d = n & 7;
                int dy = dyp - h;
                float a = 0.f;
                if (dy >= 0 && dy < FIELD && dx < 7) {
                    int tap = dy * 7 + dx;
#pragma unroll
                    for (int c = 0; c < Cc; ++c) {
                        float kv = (c == j) ? 0.f : kw[(tap * Cc + j) * Cc + c];
                        a = fmaf(kv, sw[c * Cc + d], a);
                    }
                }
                wtab[(s * 16 + n) * 8 + j] = f2bf(a);
            }
        }
    }

    const long long STRD = (long long)BB * HH * WW / IP;
    const long long pb = (long long)blockIdx.x * 256 + threadIdx.x;

    // --- issue all IP*2 loads up front (read-once: nontemporal) ---
    fvec4 xr[IP][2];
#pragma unroll
    for (int k = 0; k < IP; ++k) {
        const fvec4* xp = (const fvec4*)(x + (pb + k * STRD) * Cc);
        xr[k][0] = __builtin_nontemporal_load(xp);
        xr[k][1] = __builtin_nontemporal_load(xp + 1);
    }

#pragma unroll
    for (int k = 0; k < IP; ++k) {
        const long long p = pb + k * STRD;
        float xv[Cc] = {xr[k][0].x, xr[k][0].y, xr[k][0].z, xr[k][0].w,
                        xr[k][1].x, xr[k][1].y, xr[k][1].z, xr[k][1].w};
        float m = xv[0];
#pragma unroll
        for (int c = 1; c < Cc; ++c) m = fmaxf(m, xv[c]);
        float s = 0.f, e[Cc];
#pragma unroll
        for (int c = 0; c < Cc; ++c) { e[c] = __expf(xv[c] - m); s += e[c]; }
        float inv = 1.f / s;
        uint4 qo;
        qo.x = f2bf(e[0] * inv) | ((unsigned)f2bf(e[1] * inv) << 16);
        qo.y = f2bf(e[2] * inv) | ((unsigned)f2bf(e[3] * inv) << 16);
        qo.z = f2bf(e[4] * inv) | ((unsigned)f2bf(e[5] * inv) << 16);
        qo.w = f2bf(e[6] * inv) | ((unsigned)f2bf(e[7] * inv) << 16);
        q0[p] = qo;

        float lse = m + __logf(s);
        float u[Cc];
#pragma unroll
        for (int c = 0; c < Cc; ++c) u[c] = fminf(lse - xv[c], UCLIP);
        float vv[Cc];
#pragma unroll
        for (int d = 0; d < Cc; ++d) {
            float a = sb[d];
#pragma unroll
            for (int c = 0; c < Cc; ++c) a = fmaf(-u[c], sw[c * Cc + d], a);
            vv[d] = a;
        }
        if (half) {
            uint4 vo;
            vo.x = f2h(vv[0]) | ((unsigned)f2h(vv[1]) << 16);
            vo.y = f2h(vv[2]) | ((unsigned)f2h(vv[3]) << 16);
            vo.z = f2h(vv[4]) | ((unsigned)f2h(vv[5]) << 16);
            vo.w = f2h(vv[6]) | ((unsigned)f2h(vv[7]) << 16);
            vh[p] = vo;
        } else {
            float4* vp = (float4*)(vf + p * Cc);
            vp[0] = make_float4(vv[0], vv[1], vv[2], vv[3]);
            vp[1] = make_float4(vv[4], vv[5], vv[6], vv[7]);
        }
    }
}

// ---------------------------------------------------------------------------
// mrf_iter: R7/R8/R11/R14-verified iteration kernel (VHALF: v fp16 vs fp32).
// NB=4 batch pipeline on double-buffered qs; operand-swapped row-pair MFMA
// (dx-major K, read-dedup, 0 bank conflicts); in-register softmax via
// shfl_xor(16); single barrier per tile. Last iteration writes fp32 logits
// with nontemporal stores (151 MB never re-read -> don't pollute L2/L3).
// q staging loads and q_out stores are CACHED (best measured config, R14).
// ---------------------------------------------------------------------------
template<int VHALF>
__global__ __launch_bounds__(512)
void mrf_iter(const uint4* __restrict__ qin,
              const unsigned short* __restrict__ wtab,
              const void* __restrict__ vsrc,
              uint4* __restrict__ qout,
              float* __restrict__ lout,
              int last) {
    __shared__ __align__(16) uint4 qs[2][NSTG];

    const int tid = threadIdx.x;
    const int wv  = tid >> 6;
    const int l   = tid & 63;
    const int m   = l & 15;
    const int g   = l >> 4;

    const int w0 = blockIdx.x * TW;
    const int h0 = blockIdx.y * TH;
    const int b0 = blockIdx.z * NB;

    const int r0 = 4 * (wv >> 1);
    const int cx = 16 * (wv & 1);

    const int p   = g & 1;
    const int row = r0 + 2 * p + (g >> 1);
    const int px  = cx + m;
    const long long pixoff = (long long)(h0 + row) * WW + (w0 + px);
    const long long BSTR   = (long long)HH * WW;

    short8 bw[8][2];
#pragma unroll
    for (int dyq = 0; dyq < 8; ++dyq)
#pragma unroll
        for (int dxb = 0; dxb < 2; ++dxb) {
            int s = dyq * 8 + 4 * dxb + g;
            uint4 t = *(const uint4*)(wtab + (s * 16 + m) * 8);
            bw[dyq][dxb] = __builtin_bit_cast(short8, t);
        }

    const int sy0 = tid / QSTR, sx0 = tid - sy0 * QSTR;
    const int gh0 = h0 + sy0 - PAD, gw0 = w0 + sx0 - PAD;
    const bool in0 = (gh0 >= 0 && gh0 < HH && gw0 >= 0 && gw0 < WW);
    const long long off0 = (long long)gh0 * WW + gw0;
    const int  s1  = tid + 512;
    const bool has1 = (s1 < NSTG);
    const int sy1 = s1 / QSTR, sx1 = s1 - sy1 * QSTR;
    const int gh1 = h0 + sy1 - PAD, gw1 = w0 + sx1 - PAD;
    const bool in1 = has1 && (gh1 >= 0 && gh1 < HH && gw1 >= 0 && gw1 < WW);
    const long long off1 = (long long)gh1 * WW + gw1;

    const uint4* qb = qin + b0 * BSTR;
    const uint4  zz = make_uint4(0, 0, 0, 0);

    uint4 c0 = in0 ? qb[off0] : zz;
    uint4 c1 = in1 ? qb[off1] : zz;
    uint4  vhv = zz;
    float4 v0, v1;
    if constexpr (VHALF) {
        vhv = ((const uint4*)vsrc)[b0 * BSTR + pixoff];
    } else {
        const float4* vp0 = (const float4*)((const float*)vsrc + (b0 * BSTR + pixoff) * Cc);
        v0 = vp0[0]; v1 = vp0[1];
    }
    qs[0][tid] = c0;
    if (has1) qs[0][s1] = c1;
    __syncthreads();

#pragma unroll
    for (int t = 0; t < NB; ++t) {
        uint4 n0 = zz, n1 = zz, vhn = zz;
        float4 vn0 = make_float4(0.f, 0.f, 0.f, 0.f), vn1 = vn0;
        if (t + 1 < NB) {
            const uint4* qbn = qb + (t + 1) * BSTR;
            n0 = in0 ? qbn[off0] : zz;
            n1 = in1 ? qbn[off1] : zz;
            if constexpr (VHALF) {
                vhn = ((const uint4*)vsrc)[(b0 + t + 1) * BSTR + pixoff];
            } else {
                const float4* vpn = (const float4*)((const float*)vsrc + ((b0 + t + 1) * BSTR + pixoff) * Cc);
                vn0 = vpn[0]; vn1 = vpn[1];
            }
        }

        f32x4 acc0 = (f32x4){0.f, 0.f, 0.f, 0.f};
        f32x4 acc1 = (f32x4){0.f, 0.f, 0.f, 0.f};
        const uint4* Q = qs[t & 1];
        const int colbase = cx + m + g;
#pragma unroll
        for (int dyp = 0; dyp < 10; ++dyp) {
            const int rb = (r0 + dyp) * QSTR + colbase;
#pragma unroll
            for (int dxb = 0; dxb < 2; ++dxb) {
                short8 qv = *(const short8*)&Q[rb + 4 * dxb];
                if (dyp < 8)
                    acc0 = __builtin_amdgcn_mfma_f32_16x16x32_bf16(bw[dyp][dxb], qv, acc0, 0, 0, 0);
                if (dyp >= 2)
                    acc1 = __builtin_amdgcn_mfma_f32_16x16x32_bf16(bw[dyp - 2][dxb], qv, acc1, 0, 0, 0);
            }
        }

        float o[Cc];
#pragma unroll
        for (int tt = 0; tt < 4; ++tt) {
            float s0v = __shfl_xor(acc0[tt], 16);
            float s1v = __shfl_xor(acc1[tt], 16);
            o[tt]     = p ? s1v      : acc0[tt];
            o[4 + tt] = p ? acc1[tt] : s0v;
        }

        float vv[Cc];
        if constexpr (VHALF) {
            vv[0] = hlo(vhv.x); vv[1] = hhi(vhv.x);
            vv[2] = hlo(vhv.y); vv[3] = hhi(vhv.y);
            vv[4] = hlo(vhv.z); vv[5] = hhi(vhv.z);
            vv[6] = hlo(vhv.w); vv[7] = hhi(vhv.w);
        } else {
            vv[0] = v0.x; vv[1] = v0.y; vv[2] = v0.z; vv[3] = v0.w;
            vv[4] = v1.x; vv[5] = v1.y; vv[6] = v1.z; vv[7] = v1.w;
        }
#pragma unroll
        for (int d = 0; d < Cc; ++d) o[d] = vv[d] - o[d];
        const long long pix = (b0 + t) * BSTR + pixoff;
        if (last) {
            fvec4* op = (fvec4*)(lout + pix * Cc);
            fvec4 w0v = {o[0], o[1], o[2], o[3]};
            fvec4 w1v = {o[4], o[5], o[6], o[7]};
            __builtin_nontemporal_store(w0v, op);
            __builtin_nontemporal_store(w1v, op + 1);
        } else {
            float mm = o[0];
#pragma unroll
            for (int d = 1; d < Cc; ++d) mm = fmaxf(mm, o[d]);
            float ss = 0.f, e[Cc];
#pragma unroll
            for (int d = 0; d < Cc; ++d) { e[d] = __expf(o[d] - mm); ss += e[d]; }
            float inv = 1.f / ss;
            uint4 qo;
            qo.x = f2bf(e[0] * inv) | ((unsigned)f2bf(e[1] * inv) << 16);
            qo.y = f2bf(e[2] * inv) | ((unsigned)f2bf(e[3] * inv) << 16);
            qo.z = f2bf(e[4] * inv) | ((unsigned)f2bf(e[5] * inv) << 16);
            qo.w = f2bf(e[6] * inv) | ((unsigned)f2bf(e[7] * inv) << 16);
            qout[pix] = qo;
        }

        if (t + 1 < NB) {
            qs[(t + 1) & 1][tid] = n0;
            if (has1) qs[(t + 1) & 1][s1] = n1;
            __syncthreads();
            if constexpr (VHALF) { vhv = vhn; } else { v0 = vn0; v1 = vn1; }
        }
    }
}

extern "C" void kernel_launch(void* const* d_in, const int* in_sizes, int n_in,
                              void* d_out, int out_size, void* d_ws, size_t ws_size,
                              hipStream_t stream) {
    (void)in_sizes; (void)n_in; (void)out_size;
    const float* x  = (const float*)d_in[0];   // [32,384,384,8]
    const float* kw = (const float*)d_in[1];   // [7,7,8,8]
    const float* sw = (const float*)d_in[2];   // [8,8]
    const float* sb = (const float*)d_in[3];   // [8]

    const size_t QSZ = (size_t)BB * HH * WW * 16;   // 75,497,472 B (bf16x8)
    const size_t VSZ = (size_t)BB * HH * WW * 16;   // 75,497,472 B (fp16x8)
    uint4* qA = (uint4*)d_ws;
    uint4* qB = (uint4*)((char*)d_ws + QSZ);

    const long long npix = (long long)BB * HH * WW;
    dim3 grid(WW / TW, HH / TH, BB / NB);   // 12 x 24 x 8
    const int initBlocks = (int)(npix / (256 * IP));   // 4608

    if (ws_size >= 2 * QSZ + VSZ + 16384) {
        // fp16-v path: whole iteration working set {qA,qB,v} = 226.5 MB < L3
        uint4* vh = (uint4*)((char*)d_ws + 2 * QSZ);
        unsigned short* wt = (unsigned short*)((char*)d_ws + 2 * QSZ + VSZ);
        init_qv<<<initBlocks, 256, 0, stream>>>(x, sw, sb, qA, nullptr, vh, 1, kw, wt);
        mrf_iter<1><<<grid, 512, 0, stream>>>(qA, wt, vh, qB, nullptr, 0);
        mrf_iter<1><<<grid, 512, 0, stream>>>(qB, wt, vh, qA, nullptr, 0);
        mrf_iter<1><<<grid, 512, 0, stream>>>(qA, wt, vh, qB, nullptr, 0);
        mrf_iter<1><<<grid, 512, 0, stream>>>(qB, wt, vh, qA, nullptr, 0);
        mrf_iter<1><<<grid, 512, 0, stream>>>(qA, wt, vh, nullptr, (float*)d_out, 1);
    } else {
        // fallback: fp32-v-in-d_out path (R7-verified structure)
        float* vbuf = (float*)d_out;
        unsigned short* wt = (unsigned short*)((char*)d_ws + 2 * QSZ);
        init_qv<<<initBlocks, 256, 0, stream>>>(x, sw, sb, qA, vbuf, nullptr, 0, kw, wt);
        mrf_iter<0><<<grid, 512, 0, stream>>>(qA, wt, vbuf, qB, nullptr, 0);
        mrf_iter<0><<<grid, 512, 0, stream>>>(qB, wt, vbuf, qA, nullptr, 0);
        mrf_iter<0><<<grid, 512, 0, stream>>>(qA, wt, vbuf, qB, nullptr, 0);
        mrf_iter<0><<<grid, 512, 0, stream>>>(qB, wt, vbuf, qA, nullptr, 0);
        mrf_iter<0><<<grid, 512, 0, stream>>>(qA, wt, vbuf, nullptr, (float*)d_out, 1);
    }
}